// Round 8
// baseline (356.187 us; speedup 1.0000x reference)
//
#include <hip/hip_runtime.h>

typedef __attribute__((ext_vector_type(8))) short short8;
typedef __attribute__((ext_vector_type(4))) float f32x4;

#define MFMA16(a, b, c) __builtin_amdgcn_mfma_f32_16x16x32_bf16(a, b, c, 0, 0, 0)

// B=4, S=2048, D=1024, H=16, HD=64
#define SEQ 2048
#define DIM 1024
#define NH 16
#define HD 64
#define LOG2E 1.4426950408889634f

__device__ __forceinline__ ushort f2bf(float f) {
  union { float f; unsigned u; } v; v.f = f;
  unsigned r = (v.u + 0x7FFFu + ((v.u >> 16) & 1u)) >> 16;
  return (ushort)r;
}

// 1-instruction bf16 round (RNE) via packed convert
__device__ __forceinline__ ushort bf1(float f) {
  unsigned r;
  asm("v_cvt_pk_bf16_f32 %0, %1, %2" : "=v"(r) : "v"(f), "v"(f));
  return (ushort)(r & 0xffffu);
}

__device__ __forceinline__ float exp2fn(float x) {
#if __has_builtin(__builtin_amdgcn_exp2f)
  return __builtin_amdgcn_exp2f(x);
#else
  return exp2f(x);
#endif
}

// ---------------- prep: a{q,k,v} = bf16(inputs + pos_emb) ----------------
__global__ __launch_bounds__(256) void prep_a(
    const float* __restrict__ x, const float* __restrict__ pq,
    const float* __restrict__ pk, const float* __restrict__ pv,
    ushort* __restrict__ aq, ushort* __restrict__ ak, ushort* __restrict__ av) {
  int i = (blockIdx.x * 256 + threadIdx.x) * 4;
  int pi = i & (SEQ * DIM - 1);
  float4 xv = *(const float4*)(x + i);
  float4 q4 = *(const float4*)(pq + pi);
  float4 k4 = *(const float4*)(pk + pi);
  float4 v4 = *(const float4*)(pv + pi);
  ushort4 o;
  o.x = f2bf(xv.x + q4.x); o.y = f2bf(xv.y + q4.y);
  o.z = f2bf(xv.z + q4.z); o.w = f2bf(xv.w + q4.w);
  *(ushort4*)(aq + i) = o;
  o.x = f2bf(xv.x + k4.x); o.y = f2bf(xv.y + k4.y);
  o.z = f2bf(xv.z + k4.z); o.w = f2bf(xv.w + k4.w);
  *(ushort4*)(ak + i) = o;
  o.x = f2bf(xv.x + v4.x); o.y = f2bf(xv.y + v4.y);
  o.z = f2bf(xv.z + v4.z); o.w = f2bf(xv.w + v4.w);
  *(ushort4*)(av + i) = o;
}

// ------------- prep: 4x W [K=1024][N=1024] fp32 -> Wt [N][K] bf16, fused -------------
__global__ __launch_bounds__(256) void transpose_all(
    const float* __restrict__ w0, const float* __restrict__ w1,
    const float* __restrict__ w2, const float* __restrict__ w3,
    ushort* __restrict__ d0, ushort* __restrict__ d1,
    ushort* __restrict__ d2, ushort* __restrict__ d3) {
  const int z = blockIdx.z;
  const float* src = z == 0 ? w0 : z == 1 ? w1 : z == 2 ? w2 : w3;
  ushort* dst = z == 0 ? d0 : z == 1 ? d1 : z == 2 ? d2 : d3;
  __shared__ float t[32][33];
  int tx = threadIdx.x & 31, ty = threadIdx.x >> 5;
  int x0 = blockIdx.x * 32, y0 = blockIdx.y * 32;
#pragma unroll
  for (int j = 0; j < 32; j += 8) t[ty + j][tx] = src[(size_t)(y0 + ty + j) * DIM + x0 + tx];
  __syncthreads();
#pragma unroll
  for (int j = 0; j < 32; j += 8)
    dst[(size_t)(x0 + ty + j) * DIM + y0 + tx] = f2bf(t[tx][ty + j]);
}

// ---------------- fused QKV GEMM: grid (64, 24); proj = y>>3 -----------------
// Reg-staged 128x128 tile, LDA=40 (round-5 verified body). proj 0/1 -> bf16
// [B,H,S,HD] (Q scaled by 0.125*log2e); proj 2 -> bf16 [B,H,HD,S] (V^T).
__global__ __launch_bounds__(256) void gemm_qkv(
    const ushort* __restrict__ aq, const ushort* __restrict__ ak,
    const ushort* __restrict__ av, const ushort* __restrict__ wqT,
    const ushort* __restrict__ wkT, const ushort* __restrict__ wvT,
    const float* __restrict__ bq, const float* __restrict__ bk,
    const float* __restrict__ bv, ushort* __restrict__ Qb,
    ushort* __restrict__ Kb, ushort* __restrict__ VTb) {
  constexpr int K = 1024, LDA = 40;
  __shared__ __align__(16) ushort As[128 * LDA];
  __shared__ __align__(16) ushort Bs[128 * LDA];
  const int proj = blockIdx.y >> 3, bn = blockIdx.y & 7, bm = blockIdx.x;
  const ushort* A = proj == 0 ? aq : proj == 1 ? ak : av;
  const ushort* Bt = proj == 0 ? wqT : proj == 1 ? wkT : wvT;
  const float* bias = proj == 0 ? bq : proj == 1 ? bk : bv;
  ushort* outp = proj == 0 ? Qb : proj == 1 ? Kb : VTb;
  const float scale = proj == 0 ? 0.125f * LOG2E : 1.0f;

  const int tid = threadIdx.x;
  const int wave = tid >> 6, lane = tid & 63;
  const int wr = wave >> 1, wc = wave & 1;
  const int g = lane >> 4, l15 = lane & 15;
  const int r0 = tid >> 2, c0 = (tid & 3) * 8;
  const ushort* Ap = A + (size_t)(bm * 128 + r0) * K + c0;
  const ushort* Bp = Bt + (size_t)(bn * 128 + r0) * K + c0;
  f32x4 acc[4][4] = {};

  uint4 ra0 = *(const uint4*)(Ap);
  uint4 ra1 = *(const uint4*)(Ap + (size_t)64 * K);
  uint4 rb0 = *(const uint4*)(Bp);
  uint4 rb1 = *(const uint4*)(Bp + (size_t)64 * K);

  for (int kt = 0; kt < K; kt += 32) {
    __syncthreads();
    *(uint4*)&As[r0 * LDA + c0] = ra0;
    *(uint4*)&As[(r0 + 64) * LDA + c0] = ra1;
    *(uint4*)&Bs[r0 * LDA + c0] = rb0;
    *(uint4*)&Bs[(r0 + 64) * LDA + c0] = rb1;
    __syncthreads();
    if (kt + 32 < K) {
      ra0 = *(const uint4*)(Ap + kt + 32);
      ra1 = *(const uint4*)(Ap + (size_t)64 * K + kt + 32);
      rb0 = *(const uint4*)(Bp + kt + 32);
      rb1 = *(const uint4*)(Bp + (size_t)64 * K + kt + 32);
    }
    short8 af[4], bfr[4];
#pragma unroll
    for (int m = 0; m < 4; ++m)
      af[m] = *(const short8*)&As[(wr * 64 + m * 16 + l15) * LDA + g * 8];
#pragma unroll
    for (int n = 0; n < 4; ++n)
      bfr[n] = *(const short8*)&Bs[(wc * 64 + n * 16 + l15) * LDA + g * 8];
#pragma unroll
    for (int m = 0; m < 4; ++m)
#pragma unroll
      for (int n = 0; n < 4; ++n) acc[m][n] = MFMA16(af[m], bfr[n], acc[m][n]);
  }

#pragma unroll
  for (int m = 0; m < 4; ++m) {
    int row = bm * 128 + wr * 64 + m * 16 + g * 4;
#pragma unroll
    for (int n = 0; n < 4; ++n) {
      int col = bn * 128 + wc * 64 + n * 16 + l15;
      float bv2 = bias[col];
#pragma unroll
      for (int j = 0; j < 4; ++j) {
        float v = (acc[m][n][j] + bv2) * scale;
        int r = row + j;
        int b = r >> 11, s = r & (SEQ - 1), h = col >> 6, hd = col & (HD - 1);
        if (proj < 2)
          outp[((size_t)((b * NH + h) * SEQ + s)) * HD + hd] = f2bf(v);
        else
          outp[((size_t)((b * NH + h) * HD + hd)) * SEQ + s] = f2bf(v);
      }
    }
  }
}

// ---------------- out-proj GEMM (round-5 verified, MODE 1) ----------------
__global__ __launch_bounds__(256) void gemm_out(
    const ushort* __restrict__ A, const ushort* __restrict__ Bt,
    const float* __restrict__ bias, float* __restrict__ outp) {
  constexpr int K = 1024, LDA = 40;
  __shared__ __align__(16) ushort As[128 * LDA];
  __shared__ __align__(16) ushort Bs[128 * LDA];
  const int tid = threadIdx.x;
  const int wave = tid >> 6, lane = tid & 63;
  const int wr = wave >> 1, wc = wave & 1;
  const int g = lane >> 4, l15 = lane & 15;
  const int bm = blockIdx.x, bn = blockIdx.y;
  const int r0 = tid >> 2, c0 = (tid & 3) * 8;
  const ushort* Ap = A + (size_t)(bm * 128 + r0) * K + c0;
  const ushort* Bp = Bt + (size_t)(bn * 128 + r0) * K + c0;
  f32x4 acc[4][4] = {};

  uint4 ra0 = *(const uint4*)(Ap);
  uint4 ra1 = *(const uint4*)(Ap + (size_t)64 * K);
  uint4 rb0 = *(const uint4*)(Bp);
  uint4 rb1 = *(const uint4*)(Bp + (size_t)64 * K);

  for (int kt = 0; kt < K; kt += 32) {
    __syncthreads();
    *(uint4*)&As[r0 * LDA + c0] = ra0;
    *(uint4*)&As[(r0 + 64) * LDA + c0] = ra1;
    *(uint4*)&Bs[r0 * LDA + c0] = rb0;
    *(uint4*)&Bs[(r0 + 64) * LDA + c0] = rb1;
    __syncthreads();
    if (kt + 32 < K) {
      ra0 = *(const uint4*)(Ap + kt + 32);
      ra1 = *(const uint4*)(Ap + (size_t)64 * K + kt + 32);
      rb0 = *(const uint4*)(Bp + kt + 32);
      rb1 = *(const uint4*)(Bp + (size_t)64 * K + kt + 32);
    }
    short8 af[4], bfr[4];
#pragma unroll
    for (int m = 0; m < 4; ++m)
      af[m] = *(const short8*)&As[(wr * 64 + m * 16 + l15) * LDA + g * 8];
#pragma unroll
    for (int n = 0; n < 4; ++n)
      bfr[n] = *(const short8*)&Bs[(wc * 64 + n * 16 + l15) * LDA + g * 8];
#pragma unroll
    for (int m = 0; m < 4; ++m)
#pragma unroll
      for (int n = 0; n < 4; ++n) acc[m][n] = MFMA16(af[m], bfr[n], acc[m][n]);
  }

#pragma unroll
  for (int m = 0; m < 4; ++m) {
    int row = bm * 128 + wr * 64 + m * 16 + g * 4;
#pragma unroll
    for (int n = 0; n < 4; ++n) {
      int col = bn * 128 + wc * 64 + n * 16 + l15;
      float bv = bias[col];
#pragma unroll
      for (int j = 0; j < 4; ++j)
        outp[(size_t)(row + j) * DIM + col] = acc[m][n][j] + bv;
    }
  }
}

// ---------------- flash attention v8: round-5 mapping + bias reg ping-pong ----
// grid 1024 = 16 q-tiles x 64 bh (XCD-swizzled). 4 waves; each wave owns 32 q-rows.
// Q as A-operand, K as B-operand (verified). No-max exp2 softmax (verified).
// NEW: next tile's abias/kvbias prefetched into a ping-pong register set, so the
// ~L3-latency scalar loads drain under a full tile of compute.
__global__ __launch_bounds__(256) void attn8(
    const ushort* __restrict__ Q, const ushort* __restrict__ K,
    const ushort* __restrict__ VT, const float* __restrict__ abias,
    const float* __restrict__ kvbias, ushort* __restrict__ X) {
  constexpr int LDK = 72, LDV = 72, LDP = 72;
  constexpr int NT = SEQ / 64;
  __shared__ __align__(16) ushort Ks[64 * LDK];      // [key][d]
  __shared__ __align__(16) ushort Vs[64 * LDV];      // [d][key]  (V^T tile)
  __shared__ __align__(16) ushort Ps[4][32 * LDP];   // per-wave [q_local][key]
  const int tid = threadIdx.x;
  const int w = tid >> 6, lane = tid & 63, g = lane >> 4, l15 = lane & 15;
  const int px = blockIdx.x;
  const int qt = (px & 7) | ((px >> 9) << 3);   // bijective XCD swizzle
  const int bh = (px >> 3) & 63;
  const int b = bh >> 4, h = bh & (NH - 1);
  const int q0 = qt * 128;

  // Q fragments as A-operand: row = l15, k = c*32 + g*8 (+i)
  short8 qf[2][2];
#pragma unroll
  for (int sub = 0; sub < 2; ++sub) {
    const ushort* qp = Q + ((size_t)bh * SEQ + q0 + w * 32 + sub * 16 + l15) * HD;
#pragma unroll
    for (int c = 0; c < 2; ++c) qf[sub][c] = *(const short8*)(qp + c * 32 + g * 8);
  }

  f32x4 o[2][4] = {};
  float l_lane[2][4] = {};

  const int sr = tid >> 2, scc = (tid & 3) * 16;
  const ushort* Kp = K + (size_t)bh * SEQ * HD;    // [key][d]
  const ushort* Vp = VT + (size_t)bh * HD * SEQ;   // [d][key]
  const float* abp = abias + (size_t)q0 * SEQ;
  const float* kvp = kvbias + b * SEQ;

  // prologue: K/V tile 0 into regs
  uint4 ka = *(const uint4*)(Kp + (size_t)sr * HD + scc);
  uint4 kb = *(const uint4*)(Kp + (size_t)sr * HD + scc + 8);
  uint4 va = *(const uint4*)(Vp + (size_t)sr * SEQ + scc);
  uint4 vb = *(const uint4*)(Vp + (size_t)sr * SEQ + scc + 8);

  // bias ping-pong register sets
  float bkvA[4], bkvB[4];
  float abfA[2][4][4], abfB[2][4][4];

  auto loadb = [&](int kt, float (&ab)[2][4][4], float (&kv)[4]) {
    const int kk = kt * 64;
#pragma unroll
    for (int ct = 0; ct < 4; ++ct) kv[ct] = kvp[kk + ct * 16 + l15];
#pragma unroll
    for (int sub = 0; sub < 2; ++sub)
#pragma unroll
      for (int j = 0; j < 4; ++j) {
        const float* abr = abp + (size_t)(w * 32 + sub * 16 + 4 * g + j) * SEQ + kk + l15;
#pragma unroll
        for (int ct = 0; ct < 4; ++ct) ab[sub][ct][j] = abr[ct * 16];
      }
  };

  loadb(0, abfA, bkvA);  // bias tile 0

  auto tile = [&](int kt, float (&cab)[2][4][4], float (&ckv)[4],
                  float (&nab)[2][4][4], float (&nkv)[4]) {
    const int k0 = kt * 64;
    __syncthreads();  // previous tile's LDS reads complete
    *(uint4*)&Ks[sr * LDK + scc] = ka;
    *(uint4*)&Ks[sr * LDK + scc + 8] = kb;
    *(uint4*)&Vs[sr * LDV + scc] = va;
    *(uint4*)&Vs[sr * LDV + scc + 8] = vb;
    __syncthreads();

    if (kt + 1 < NT) {
      // prefetch NEXT tile's bias into the alternate reg set (full tile to drain)
      loadb(kt + 1, nab, nkv);
      // prefetch next K/V tile into regs
      ka = *(const uint4*)(Kp + (size_t)(k0 + 64 + sr) * HD + scc);
      kb = *(const uint4*)(Kp + (size_t)(k0 + 64 + sr) * HD + scc + 8);
      va = *(const uint4*)(Vp + (size_t)sr * SEQ + k0 + 64 + scc);
      vb = *(const uint4*)(Vp + (size_t)sr * SEQ + k0 + 64 + scc + 8);
    }

    // S = Q K^T : rows q (D: 4g+j), cols key (D: l15). 2 subtiles x 4 key-chunks.
    f32x4 s4[2][4];
#pragma unroll
    for (int ct = 0; ct < 4; ++ct) {
      short8 kf0 = *(const short8*)&Ks[(ct * 16 + l15) * LDK + g * 8];
      short8 kf1 = *(const short8*)&Ks[(ct * 16 + l15) * LDK + 32 + g * 8];
#pragma unroll
      for (int sub = 0; sub < 2; ++sub) {
        f32x4 z = {0.f, 0.f, 0.f, 0.f};
        f32x4 t = MFMA16(qf[sub][0], kf0, z);
        s4[sub][ct] = MFMA16(qf[sub][1], kf1, t);
      }
    }

    // no-max softmax in exp2 domain; per-lane l partials
#pragma unroll
    for (int sub = 0; sub < 2; ++sub) {
      float p[4][4];
#pragma unroll
      for (int ct = 0; ct < 4; ++ct)
#pragma unroll
        for (int j = 0; j < 4; ++j)
          p[ct][j] = exp2fn(fmaf(cab[sub][ct][j] + ckv[ct], LOG2E, s4[sub][ct][j]));
#pragma unroll
      for (int j = 0; j < 4; ++j)
        l_lane[sub][j] += (p[0][j] + p[1][j]) + (p[2][j] + p[3][j]);
#pragma unroll
      for (int ct = 0; ct < 4; ++ct)
#pragma unroll
        for (int j = 0; j < 4; ++j)
          Ps[w][(sub * 16 + 4 * g + j) * LDP + ct * 16 + l15] = bf1(p[ct][j]);
    }

    // wave-private P ready
    asm volatile("s_waitcnt lgkmcnt(0)" ::: "memory");
    __builtin_amdgcn_sched_barrier(0);

    // O += P V  (P as A: row=l15 within sub-block; V^T as B: col=l15=d)
    short8 pa[2][2];
#pragma unroll
    for (int sub = 0; sub < 2; ++sub)
#pragma unroll
      for (int ks = 0; ks < 2; ++ks)
        pa[sub][ks] = *(const short8*)&Ps[w][(sub * 16 + l15) * LDP + ks * 32 + g * 8];
#pragma unroll
    for (int ctd = 0; ctd < 4; ++ctd) {
      short8 vf0 = *(const short8*)&Vs[(ctd * 16 + l15) * LDV + g * 8];
      short8 vf1 = *(const short8*)&Vs[(ctd * 16 + l15) * LDV + 32 + g * 8];
#pragma unroll
      for (int sub = 0; sub < 2; ++sub) {
        o[sub][ctd] = MFMA16(pa[sub][0], vf0, o[sub][ctd]);
        o[sub][ctd] = MFMA16(pa[sub][1], vf1, o[sub][ctd]);
      }
    }
  };

  for (int kt = 0; kt < NT; kt += 2) {
    tile(kt, abfA, bkvA, abfB, bkvB);
    tile(kt + 1, abfB, bkvB, abfA, bkvA);
  }

  // one final l reduction per row (16-lane l15 group), then normalize + write
#pragma unroll
  for (int sub = 0; sub < 2; ++sub) {
    float inv[4];
#pragma unroll
    for (int j = 0; j < 4; ++j) {
      float l = l_lane[sub][j];
      l += __shfl_xor(l, 1);
      l += __shfl_xor(l, 2);
      l += __shfl_xor(l, 4);
      l += __shfl_xor(l, 8);
      inv[j] = 1.0f / l;
    }
#pragma unroll
    for (int ctd = 0; ctd < 4; ++ctd)
#pragma unroll
      for (int j = 0; j < 4; ++j) {
        size_t row = (size_t)b * SEQ + q0 + w * 32 + sub * 16 + 4 * g + j;
        X[row * DIM + h * HD + ctd * 16 + l15] = bf1(o[sub][ctd][j] * inv[j]);
      }
  }
}

extern "C" void kernel_launch(void* const* d_in, const int* in_sizes, int n_in,
                              void* d_out, int out_size, void* d_ws, size_t ws_size,
                              hipStream_t stream) {
  const float* inputs_q = (const float*)d_in[0];
  const float* pos_q = (const float*)d_in[1];
  const float* pos_k = (const float*)d_in[2];
  const float* pos_v = (const float*)d_in[3];
  const float* abias = (const float*)d_in[4];
  const float* kvbias = (const float*)d_in[5];
  const float* wq = (const float*)d_in[6];
  const float* bq = (const float*)d_in[7];
  const float* wk = (const float*)d_in[8];
  const float* bk = (const float*)d_in[9];
  const float* wv = (const float*)d_in[10];
  const float* bv = (const float*)d_in[11];
  const float* wo = (const float*)d_in[12];
  const float* bo = (const float*)d_in[13];

  char* ws = (char*)d_ws;
  const size_t MB = 1ull << 20;
  ushort* wqT = (ushort*)(ws + 0 * MB);
  ushort* wkT = (ushort*)(ws + 2 * MB);
  ushort* wvT = (ushort*)(ws + 4 * MB);
  ushort* woT = (ushort*)(ws + 6 * MB);
  ushort* aq = (ushort*)(ws + 8 * MB);
  ushort* ak = (ushort*)(ws + 24 * MB);
  ushort* av = (ushort*)(ws + 40 * MB);
  ushort* Qb = (ushort*)(ws + 56 * MB);
  ushort* Kb = (ushort*)(ws + 72 * MB);
  ushort* VTb = (ushort*)(ws + 88 * MB);
  ushort* Xb = (ushort*)(ws + 8 * MB);  // alias aq (dead after Q-GEMM)

  prep_a<<<8192, 256, 0, stream>>>(inputs_q, pos_q, pos_k, pos_v, aq, ak, av);
  transpose_all<<<dim3(32, 32, 4), 256, 0, stream>>>(wq, wk, wv, wo, wqT, wkT, wvT, woT);
  // fused QKV: 1536 blocks in one dispatch (proj = blockIdx.y>>3)
  gemm_qkv<<<dim3(64, 24), 256, 0, stream>>>(aq, ak, av, wqT, wkT, wvT,
                                             bq, bk, bv, Qb, Kb, VTb);
  attn8<<<1024, 256, 0, stream>>>(Qb, Kb, VTb, abias, kvbias, Xb);
  gemm_out<<<dim3(64, 8), 256, 0, stream>>>(Xb, woT, bo, (float*)d_out);
}

// Round 9
// 292.504 us; speedup vs baseline: 1.2177x; 1.2177x over previous
//
#include <hip/hip_runtime.h>

typedef __attribute__((ext_vector_type(8))) short short8;
typedef __attribute__((ext_vector_type(4))) float f32x4;

#define MFMA16(a, b, c) __builtin_amdgcn_mfma_f32_16x16x32_bf16(a, b, c, 0, 0, 0)

// B=4, S=2048, D=1024, H=16, HD=64
#define SEQ 2048
#define DIM 1024
#define NH 16
#define HD 64
#define LOG2E 1.4426950408889634f

__device__ __forceinline__ ushort f2bf(float f) {
  union { float f; unsigned u; } v; v.f = f;
  unsigned r = (v.u + 0x7FFFu + ((v.u >> 16) & 1u)) >> 16;
  return (ushort)r;
}

// 1-instruction bf16 round (RNE) via packed convert
__device__ __forceinline__ ushort bf1(float f) {
  unsigned r;
  asm("v_cvt_pk_bf16_f32 %0, %1, %2" : "=v"(r) : "v"(f), "v"(f));
  return (ushort)(r & 0xffffu);
}

__device__ __forceinline__ float exp2fn(float x) {
#if __has_builtin(__builtin_amdgcn_exp2f)
  return __builtin_amdgcn_exp2f(x);
#else
  return exp2f(x);
#endif
}

// ---------------- prep: a{q,k,v} = bf16(inputs + pos_emb) ----------------
__global__ __launch_bounds__(256) void prep_a(
    const float* __restrict__ x, const float* __restrict__ pq,
    const float* __restrict__ pk, const float* __restrict__ pv,
    ushort* __restrict__ aq, ushort* __restrict__ ak, ushort* __restrict__ av) {
  int i = (blockIdx.x * 256 + threadIdx.x) * 4;
  int pi = i & (SEQ * DIM - 1);
  float4 xv = *(const float4*)(x + i);
  float4 q4 = *(const float4*)(pq + pi);
  float4 k4 = *(const float4*)(pk + pi);
  float4 v4 = *(const float4*)(pv + pi);
  ushort4 o;
  o.x = f2bf(xv.x + q4.x); o.y = f2bf(xv.y + q4.y);
  o.z = f2bf(xv.z + q4.z); o.w = f2bf(xv.w + q4.w);
  *(ushort4*)(aq + i) = o;
  o.x = f2bf(xv.x + k4.x); o.y = f2bf(xv.y + k4.y);
  o.z = f2bf(xv.z + k4.z); o.w = f2bf(xv.w + k4.w);
  *(ushort4*)(ak + i) = o;
  o.x = f2bf(xv.x + v4.x); o.y = f2bf(xv.y + v4.y);
  o.z = f2bf(xv.z + v4.z); o.w = f2bf(xv.w + v4.w);
  *(ushort4*)(av + i) = o;
}

// ------------- prep: 4x W [K=1024][N=1024] fp32 -> Wt [N][K] bf16, fused -------------
__global__ __launch_bounds__(256) void transpose_all(
    const float* __restrict__ w0, const float* __restrict__ w1,
    const float* __restrict__ w2, const float* __restrict__ w3,
    ushort* __restrict__ d0, ushort* __restrict__ d1,
    ushort* __restrict__ d2, ushort* __restrict__ d3) {
  const int z = blockIdx.z;
  const float* src = z == 0 ? w0 : z == 1 ? w1 : z == 2 ? w2 : w3;
  ushort* dst = z == 0 ? d0 : z == 1 ? d1 : z == 2 ? d2 : d3;
  __shared__ float t[32][33];
  int tx = threadIdx.x & 31, ty = threadIdx.x >> 5;
  int x0 = blockIdx.x * 32, y0 = blockIdx.y * 32;
#pragma unroll
  for (int j = 0; j < 32; j += 8) t[ty + j][tx] = src[(size_t)(y0 + ty + j) * DIM + x0 + tx];
  __syncthreads();
#pragma unroll
  for (int j = 0; j < 32; j += 8)
    dst[(size_t)(x0 + ty + j) * DIM + y0 + tx] = f2bf(t[tx][ty + j]);
}

// ---------------- fused QKV GEMM: grid (64, 24); proj = y>>3 -----------------
__global__ __launch_bounds__(256) void gemm_qkv(
    const ushort* __restrict__ aq, const ushort* __restrict__ ak,
    const ushort* __restrict__ av, const ushort* __restrict__ wqT,
    const ushort* __restrict__ wkT, const ushort* __restrict__ wvT,
    const float* __restrict__ bq, const float* __restrict__ bk,
    const float* __restrict__ bv, ushort* __restrict__ Qb,
    ushort* __restrict__ Kb, ushort* __restrict__ VTb) {
  constexpr int K = 1024, LDA = 40;
  __shared__ __align__(16) ushort As[128 * LDA];
  __shared__ __align__(16) ushort Bs[128 * LDA];
  const int proj = blockIdx.y >> 3, bn = blockIdx.y & 7, bm = blockIdx.x;
  const ushort* A = proj == 0 ? aq : proj == 1 ? ak : av;
  const ushort* Bt = proj == 0 ? wqT : proj == 1 ? wkT : wvT;
  const float* bias = proj == 0 ? bq : proj == 1 ? bk : bv;
  ushort* outp = proj == 0 ? Qb : proj == 1 ? Kb : VTb;
  const float scale = proj == 0 ? 0.125f * LOG2E : 1.0f;

  const int tid = threadIdx.x;
  const int wave = tid >> 6, lane = tid & 63;
  const int wr = wave >> 1, wc = wave & 1;
  const int g = lane >> 4, l15 = lane & 15;
  const int r0 = tid >> 2, c0 = (tid & 3) * 8;
  const ushort* Ap = A + (size_t)(bm * 128 + r0) * K + c0;
  const ushort* Bp = Bt + (size_t)(bn * 128 + r0) * K + c0;
  f32x4 acc[4][4] = {};

  uint4 ra0 = *(const uint4*)(Ap);
  uint4 ra1 = *(const uint4*)(Ap + (size_t)64 * K);
  uint4 rb0 = *(const uint4*)(Bp);
  uint4 rb1 = *(const uint4*)(Bp + (size_t)64 * K);

  for (int kt = 0; kt < K; kt += 32) {
    __syncthreads();
    *(uint4*)&As[r0 * LDA + c0] = ra0;
    *(uint4*)&As[(r0 + 64) * LDA + c0] = ra1;
    *(uint4*)&Bs[r0 * LDA + c0] = rb0;
    *(uint4*)&Bs[(r0 + 64) * LDA + c0] = rb1;
    __syncthreads();
    if (kt + 32 < K) {
      ra0 = *(const uint4*)(Ap + kt + 32);
      ra1 = *(const uint4*)(Ap + (size_t)64 * K + kt + 32);
      rb0 = *(const uint4*)(Bp + kt + 32);
      rb1 = *(const uint4*)(Bp + (size_t)64 * K + kt + 32);
    }
    short8 af[4], bfr[4];
#pragma unroll
    for (int m = 0; m < 4; ++m)
      af[m] = *(const short8*)&As[(wr * 64 + m * 16 + l15) * LDA + g * 8];
#pragma unroll
    for (int n = 0; n < 4; ++n)
      bfr[n] = *(const short8*)&Bs[(wc * 64 + n * 16 + l15) * LDA + g * 8];
#pragma unroll
    for (int m = 0; m < 4; ++m)
#pragma unroll
      for (int n = 0; n < 4; ++n) acc[m][n] = MFMA16(af[m], bfr[n], acc[m][n]);
  }

#pragma unroll
  for (int m = 0; m < 4; ++m) {
    int row = bm * 128 + wr * 64 + m * 16 + g * 4;
#pragma unroll
    for (int n = 0; n < 4; ++n) {
      int col = bn * 128 + wc * 64 + n * 16 + l15;
      float bv2 = bias[col];
#pragma unroll
      for (int j = 0; j < 4; ++j) {
        float v = (acc[m][n][j] + bv2) * scale;
        int r = row + j;
        int b = r >> 11, s = r & (SEQ - 1), h = col >> 6, hd = col & (HD - 1);
        if (proj < 2)
          outp[((size_t)((b * NH + h) * SEQ + s)) * HD + hd] = f2bf(v);
        else
          outp[((size_t)((b * NH + h) * HD + hd)) * SEQ + s] = f2bf(v);
      }
    }
  }
}

// ---------------- out-proj GEMM (round-5 verified, MODE 1) ----------------
__global__ __launch_bounds__(256) void gemm_out(
    const ushort* __restrict__ A, const ushort* __restrict__ Bt,
    const float* __restrict__ bias, float* __restrict__ outp) {
  constexpr int K = 1024, LDA = 40;
  __shared__ __align__(16) ushort As[128 * LDA];
  __shared__ __align__(16) ushort Bs[128 * LDA];
  const int tid = threadIdx.x;
  const int wave = tid >> 6, lane = tid & 63;
  const int wr = wave >> 1, wc = wave & 1;
  const int g = lane >> 4, l15 = lane & 15;
  const int bm = blockIdx.x, bn = blockIdx.y;
  const int r0 = tid >> 2, c0 = (tid & 3) * 8;
  const ushort* Ap = A + (size_t)(bm * 128 + r0) * K + c0;
  const ushort* Bp = Bt + (size_t)(bn * 128 + r0) * K + c0;
  f32x4 acc[4][4] = {};

  uint4 ra0 = *(const uint4*)(Ap);
  uint4 ra1 = *(const uint4*)(Ap + (size_t)64 * K);
  uint4 rb0 = *(const uint4*)(Bp);
  uint4 rb1 = *(const uint4*)(Bp + (size_t)64 * K);

  for (int kt = 0; kt < K; kt += 32) {
    __syncthreads();
    *(uint4*)&As[r0 * LDA + c0] = ra0;
    *(uint4*)&As[(r0 + 64) * LDA + c0] = ra1;
    *(uint4*)&Bs[r0 * LDA + c0] = rb0;
    *(uint4*)&Bs[(r0 + 64) * LDA + c0] = rb1;
    __syncthreads();
    if (kt + 32 < K) {
      ra0 = *(const uint4*)(Ap + kt + 32);
      ra1 = *(const uint4*)(Ap + (size_t)64 * K + kt + 32);
      rb0 = *(const uint4*)(Bp + kt + 32);
      rb1 = *(const uint4*)(Bp + (size_t)64 * K + kt + 32);
    }
    short8 af[4], bfr[4];
#pragma unroll
    for (int m = 0; m < 4; ++m)
      af[m] = *(const short8*)&As[(wr * 64 + m * 16 + l15) * LDA + g * 8];
#pragma unroll
    for (int n = 0; n < 4; ++n)
      bfr[n] = *(const short8*)&Bs[(wc * 64 + n * 16 + l15) * LDA + g * 8];
#pragma unroll
    for (int m = 0; m < 4; ++m)
#pragma unroll
      for (int n = 0; n < 4; ++n) acc[m][n] = MFMA16(af[m], bfr[n], acc[m][n]);
  }

#pragma unroll
  for (int m = 0; m < 4; ++m) {
    int row = bm * 128 + wr * 64 + m * 16 + g * 4;
#pragma unroll
    for (int n = 0; n < 4; ++n) {
      int col = bn * 128 + wc * 64 + n * 16 + l15;
      float bv = bias[col];
#pragma unroll
      for (int j = 0; j < 4; ++j)
        outp[(size_t)(row + j) * DIM + col] = acc[m][n][j] + bv;
    }
  }
}

// ---------------- flash attention v9: round-5 kernel + bias issue hoisted ----
// grid 1024 = 16 q-tiles x 64 bh (XCD-swizzled). 4 waves; each wave owns 32 q-rows
// (2 subtiles of 16). Q as A-operand, K as B-operand. No-max exp2 softmax.
// Only change vs round-5: this tile's bias loads are ISSUED before the two
// staging barriers (same registers, same consumers) so they drain under
// sync + ds_write + sync instead of stalling softmax.
__global__ __launch_bounds__(256) void attn9(
    const ushort* __restrict__ Q, const ushort* __restrict__ K,
    const ushort* __restrict__ VT, const float* __restrict__ abias,
    const float* __restrict__ kvbias, ushort* __restrict__ X) {
  constexpr int LDK = 72, LDV = 72, LDP = 72;
  __shared__ __align__(16) ushort Ks[64 * LDK];      // [key][d]
  __shared__ __align__(16) ushort Vs[64 * LDV];      // [d][key]  (V^T tile)
  __shared__ __align__(16) ushort Ps[4][32 * LDP];   // per-wave [q_local][key]
  const int tid = threadIdx.x;
  const int w = tid >> 6, lane = tid & 63, g = lane >> 4, l15 = lane & 15;
  const int px = blockIdx.x;
  const int qt = (px & 7) | ((px >> 9) << 3);   // bijective XCD swizzle
  const int bh = (px >> 3) & 63;
  const int b = bh >> 4, h = bh & (NH - 1);
  const int q0 = qt * 128;

  // Q fragments as A-operand: row = l15, k = c*32 + g*8 (+i)
  short8 qf[2][2];
#pragma unroll
  for (int sub = 0; sub < 2; ++sub) {
    const ushort* qp = Q + ((size_t)bh * SEQ + q0 + w * 32 + sub * 16 + l15) * HD;
#pragma unroll
    for (int c = 0; c < 2; ++c) qf[sub][c] = *(const short8*)(qp + c * 32 + g * 8);
  }

  f32x4 o[2][4] = {};
  float l_lane[2][4] = {};

  const int sr = tid >> 2, scc = (tid & 3) * 16;
  const ushort* Kp = K + (size_t)bh * SEQ * HD;    // [key][d]
  const ushort* Vp = VT + (size_t)bh * HD * SEQ;   // [d][key]
  const float* abp = abias + (size_t)q0 * SEQ;
  const float* kvp = kvbias + b * SEQ;

  // prologue: tile 0 into regs
  uint4 ka = *(const uint4*)(Kp + (size_t)sr * HD + scc);
  uint4 kb = *(const uint4*)(Kp + (size_t)sr * HD + scc + 8);
  uint4 va = *(const uint4*)(Vp + (size_t)sr * SEQ + scc);
  uint4 vb = *(const uint4*)(Vp + (size_t)sr * SEQ + scc + 8);

  for (int kt = 0; kt < SEQ / 64; ++kt) {
    const int k0 = kt * 64;

    // issue this tile's bias loads BEFORE the staging barriers (drain window)
    float bkv[4];
#pragma unroll
    for (int ct = 0; ct < 4; ++ct) bkv[ct] = kvp[k0 + ct * 16 + l15];
    float abf[2][4][4];
#pragma unroll
    for (int sub = 0; sub < 2; ++sub)
#pragma unroll
      for (int j = 0; j < 4; ++j) {
        const float* abr = abp + (size_t)(w * 32 + sub * 16 + 4 * g + j) * SEQ + k0 + l15;
#pragma unroll
        for (int ct = 0; ct < 4; ++ct) abf[sub][ct][j] = abr[ct * 16];
      }

    __syncthreads();  // previous tile's LDS reads complete
    *(uint4*)&Ks[sr * LDK + scc] = ka;
    *(uint4*)&Ks[sr * LDK + scc + 8] = kb;
    *(uint4*)&Vs[sr * LDV + scc] = va;
    *(uint4*)&Vs[sr * LDV + scc + 8] = vb;
    __syncthreads();

    // prefetch next tile into regs (overlaps all of this tile's compute)
    if (kt + 1 < SEQ / 64) {
      ka = *(const uint4*)(Kp + (size_t)(k0 + 64 + sr) * HD + scc);
      kb = *(const uint4*)(Kp + (size_t)(k0 + 64 + sr) * HD + scc + 8);
      va = *(const uint4*)(Vp + (size_t)sr * SEQ + k0 + 64 + scc);
      vb = *(const uint4*)(Vp + (size_t)sr * SEQ + k0 + 64 + scc + 8);
    }

    // S = Q K^T : rows q (D: 4g+j), cols key (D: l15). 2 subtiles x 4 key-chunks.
    f32x4 s4[2][4];
#pragma unroll
    for (int ct = 0; ct < 4; ++ct) {
      short8 kf0 = *(const short8*)&Ks[(ct * 16 + l15) * LDK + g * 8];
      short8 kf1 = *(const short8*)&Ks[(ct * 16 + l15) * LDK + 32 + g * 8];
#pragma unroll
      for (int sub = 0; sub < 2; ++sub) {
        f32x4 z = {0.f, 0.f, 0.f, 0.f};
        f32x4 t = MFMA16(qf[sub][0], kf0, z);
        s4[sub][ct] = MFMA16(qf[sub][1], kf1, t);
      }
    }

    // no-max softmax in exp2 domain; per-lane l partials (no in-loop reductions)
#pragma unroll
    for (int sub = 0; sub < 2; ++sub) {
      float p[4][4];
#pragma unroll
      for (int ct = 0; ct < 4; ++ct)
#pragma unroll
        for (int j = 0; j < 4; ++j)
          p[ct][j] = exp2fn(fmaf(abf[sub][ct][j] + bkv[ct], LOG2E, s4[sub][ct][j]));
#pragma unroll
      for (int j = 0; j < 4; ++j)
        l_lane[sub][j] += (p[0][j] + p[1][j]) + (p[2][j] + p[3][j]);
#pragma unroll
      for (int ct = 0; ct < 4; ++ct)
#pragma unroll
        for (int j = 0; j < 4; ++j)
          Ps[w][(sub * 16 + 4 * g + j) * LDP + ct * 16 + l15] = bf1(p[ct][j]);
    }

    // wave-private P ready
    asm volatile("s_waitcnt lgkmcnt(0)" ::: "memory");
    __builtin_amdgcn_sched_barrier(0);

    // O += P V  (P as A: row=l15 within sub-block; V^T as B: col=l15=d)
    short8 pa[2][2];
#pragma unroll
    for (int sub = 0; sub < 2; ++sub)
#pragma unroll
      for (int ks = 0; ks < 2; ++ks)
        pa[sub][ks] = *(const short8*)&Ps[w][(sub * 16 + l15) * LDP + ks * 32 + g * 8];
#pragma unroll
    for (int ctd = 0; ctd < 4; ++ctd) {
      short8 vf0 = *(const short8*)&Vs[(ctd * 16 + l15) * LDV + g * 8];
      short8 vf1 = *(const short8*)&Vs[(ctd * 16 + l15) * LDV + 32 + g * 8];
#pragma unroll
      for (int sub = 0; sub < 2; ++sub) {
        o[sub][ctd] = MFMA16(pa[sub][0], vf0, o[sub][ctd]);
        o[sub][ctd] = MFMA16(pa[sub][1], vf1, o[sub][ctd]);
      }
    }
  }

  // one final l reduction per row (16-lane l15 group), then normalize + write
#pragma unroll
  for (int sub = 0; sub < 2; ++sub) {
    float inv[4];
#pragma unroll
    for (int j = 0; j < 4; ++j) {
      float l = l_lane[sub][j];
      l += __shfl_xor(l, 1);
      l += __shfl_xor(l, 2);
      l += __shfl_xor(l, 4);
      l += __shfl_xor(l, 8);
      inv[j] = 1.0f / l;
    }
#pragma unroll
    for (int ctd = 0; ctd < 4; ++ctd)
#pragma unroll
      for (int j = 0; j < 4; ++j) {
        size_t row = (size_t)b * SEQ + q0 + w * 32 + sub * 16 + 4 * g + j;
        X[row * DIM + h * HD + ctd * 16 + l15] = bf1(o[sub][ctd][j] * inv[j]);
      }
  }
}

extern "C" void kernel_launch(void* const* d_in, const int* in_sizes, int n_in,
                              void* d_out, int out_size, void* d_ws, size_t ws_size,
                              hipStream_t stream) {
  const float* inputs_q = (const float*)d_in[0];
  const float* pos_q = (const float*)d_in[1];
  const float* pos_k = (const float*)d_in[2];
  const float* pos_v = (const float*)d_in[3];
  const float* abias = (const float*)d_in[4];
  const float* kvbias = (const float*)d_in[5];
  const float* wq = (const float*)d_in[6];
  const float* bq = (const float*)d_in[7];
  const float* wk = (const float*)d_in[8];
  const float* bk = (const float*)d_in[9];
  const float* wv = (const float*)d_in[10];
  const float* bv = (const float*)d_in[11];
  const float* wo = (const float*)d_in[12];
  const float* bo = (const float*)d_in[13];

  char* ws = (char*)d_ws;
  const size_t MB = 1ull << 20;
  ushort* wqT = (ushort*)(ws + 0 * MB);
  ushort* wkT = (ushort*)(ws + 2 * MB);
  ushort* wvT = (ushort*)(ws + 4 * MB);
  ushort* woT = (ushort*)(ws + 6 * MB);
  ushort* aq = (ushort*)(ws + 8 * MB);
  ushort* ak = (ushort*)(ws + 24 * MB);
  ushort* av = (ushort*)(ws + 40 * MB);
  ushort* Qb = (ushort*)(ws + 56 * MB);
  ushort* Kb = (ushort*)(ws + 72 * MB);
  ushort* VTb = (ushort*)(ws + 88 * MB);
  ushort* Xb = (ushort*)(ws + 8 * MB);  // alias aq (dead after Q-GEMM)

  prep_a<<<8192, 256, 0, stream>>>(inputs_q, pos_q, pos_k, pos_v, aq, ak, av);
  transpose_all<<<dim3(32, 32, 4), 256, 0, stream>>>(wq, wk, wv, wo, wqT, wkT, wvT, woT);
  gemm_qkv<<<dim3(64, 24), 256, 0, stream>>>(aq, ak, av, wqT, wkT, wvT,
                                             bq, bk, bv, Qb, Kb, VTb);
  attn9<<<1024, 256, 0, stream>>>(Qb, Kb, VTb, abias, kvbias, Xb);
  gemm_out<<<dim3(64, 8), 256, 0, stream>>>(Xb, woT, bo, (float*)d_out);
}

// Round 10
// 290.038 us; speedup vs baseline: 1.2281x; 1.0085x over previous
//
#include <hip/hip_runtime.h>

typedef __attribute__((ext_vector_type(8))) short short8;
typedef __attribute__((ext_vector_type(4))) float f32x4;

#define MFMA16(a, b, c) __builtin_amdgcn_mfma_f32_16x16x32_bf16(a, b, c, 0, 0, 0)

// B=4, S=2048, D=1024, H=16, HD=64
#define SEQ 2048
#define DIM 1024
#define NH 16
#define HD 64
#define LOG2E 1.4426950408889634f

__device__ __forceinline__ ushort f2bf(float f) {
  union { float f; unsigned u; } v; v.f = f;
  unsigned r = (v.u + 0x7FFFu + ((v.u >> 16) & 1u)) >> 16;
  return (ushort)r;
}

// 1-instruction bf16 round (RNE) via packed convert
__device__ __forceinline__ ushort bf1(float f) {
  unsigned r;
  asm("v_cvt_pk_bf16_f32 %0, %1, %2" : "=v"(r) : "v"(f), "v"(f));
  return (ushort)(r & 0xffffu);
}

__device__ __forceinline__ float exp2fn(float x) {
#if __has_builtin(__builtin_amdgcn_exp2f)
  return __builtin_amdgcn_exp2f(x);
#else
  return exp2f(x);
#endif
}

// ---------------- prep: a{q,k,v} = bf16(inputs + pos_emb) ----------------
__global__ __launch_bounds__(256) void prep_a(
    const float* __restrict__ x, const float* __restrict__ pq,
    const float* __restrict__ pk, const float* __restrict__ pv,
    ushort* __restrict__ aq, ushort* __restrict__ ak, ushort* __restrict__ av) {
  int i = (blockIdx.x * 256 + threadIdx.x) * 4;
  int pi = i & (SEQ * DIM - 1);
  float4 xv = *(const float4*)(x + i);
  float4 q4 = *(const float4*)(pq + pi);
  float4 k4 = *(const float4*)(pk + pi);
  float4 v4 = *(const float4*)(pv + pi);
  ushort4 o;
  o.x = f2bf(xv.x + q4.x); o.y = f2bf(xv.y + q4.y);
  o.z = f2bf(xv.z + q4.z); o.w = f2bf(xv.w + q4.w);
  *(ushort4*)(aq + i) = o;
  o.x = f2bf(xv.x + k4.x); o.y = f2bf(xv.y + k4.y);
  o.z = f2bf(xv.z + k4.z); o.w = f2bf(xv.w + k4.w);
  *(ushort4*)(ak + i) = o;
  o.x = f2bf(xv.x + v4.x); o.y = f2bf(xv.y + v4.y);
  o.z = f2bf(xv.z + v4.z); o.w = f2bf(xv.w + v4.w);
  *(ushort4*)(av + i) = o;
}

// ------------- prep: 4x W [K=1024][N=1024] fp32 -> Wt [N][K] bf16, fused -------------
__global__ __launch_bounds__(256) void transpose_all(
    const float* __restrict__ w0, const float* __restrict__ w1,
    const float* __restrict__ w2, const float* __restrict__ w3,
    ushort* __restrict__ d0, ushort* __restrict__ d1,
    ushort* __restrict__ d2, ushort* __restrict__ d3) {
  const int z = blockIdx.z;
  const float* src = z == 0 ? w0 : z == 1 ? w1 : z == 2 ? w2 : w3;
  ushort* dst = z == 0 ? d0 : z == 1 ? d1 : z == 2 ? d2 : d3;
  __shared__ float t[32][33];
  int tx = threadIdx.x & 31, ty = threadIdx.x >> 5;
  int x0 = blockIdx.x * 32, y0 = blockIdx.y * 32;
#pragma unroll
  for (int j = 0; j < 32; j += 8) t[ty + j][tx] = src[(size_t)(y0 + ty + j) * DIM + x0 + tx];
  __syncthreads();
#pragma unroll
  for (int j = 0; j < 32; j += 8)
    dst[(size_t)(x0 + ty + j) * DIM + y0 + tx] = f2bf(t[tx][ty + j]);
}

// ---------------- fused QKV GEMM: grid (64, 24); proj = y>>3 -----------------
__global__ __launch_bounds__(256) void gemm_qkv(
    const ushort* __restrict__ aq, const ushort* __restrict__ ak,
    const ushort* __restrict__ av, const ushort* __restrict__ wqT,
    const ushort* __restrict__ wkT, const ushort* __restrict__ wvT,
    const float* __restrict__ bq, const float* __restrict__ bk,
    const float* __restrict__ bv, ushort* __restrict__ Qb,
    ushort* __restrict__ Kb, ushort* __restrict__ VTb) {
  constexpr int K = 1024, LDA = 40;
  __shared__ __align__(16) ushort As[128 * LDA];
  __shared__ __align__(16) ushort Bs[128 * LDA];
  const int proj = blockIdx.y >> 3, bn = blockIdx.y & 7, bm = blockIdx.x;
  const ushort* A = proj == 0 ? aq : proj == 1 ? ak : av;
  const ushort* Bt = proj == 0 ? wqT : proj == 1 ? wkT : wvT;
  const float* bias = proj == 0 ? bq : proj == 1 ? bk : bv;
  ushort* outp = proj == 0 ? Qb : proj == 1 ? Kb : VTb;
  const float scale = proj == 0 ? 0.125f * LOG2E : 1.0f;

  const int tid = threadIdx.x;
  const int wave = tid >> 6, lane = tid & 63;
  const int wr = wave >> 1, wc = wave & 1;
  const int g = lane >> 4, l15 = lane & 15;
  const int r0 = tid >> 2, c0 = (tid & 3) * 8;
  const ushort* Ap = A + (size_t)(bm * 128 + r0) * K + c0;
  const ushort* Bp = Bt + (size_t)(bn * 128 + r0) * K + c0;
  f32x4 acc[4][4] = {};

  uint4 ra0 = *(const uint4*)(Ap);
  uint4 ra1 = *(const uint4*)(Ap + (size_t)64 * K);
  uint4 rb0 = *(const uint4*)(Bp);
  uint4 rb1 = *(const uint4*)(Bp + (size_t)64 * K);

  for (int kt = 0; kt < K; kt += 32) {
    __syncthreads();
    *(uint4*)&As[r0 * LDA + c0] = ra0;
    *(uint4*)&As[(r0 + 64) * LDA + c0] = ra1;
    *(uint4*)&Bs[r0 * LDA + c0] = rb0;
    *(uint4*)&Bs[(r0 + 64) * LDA + c0] = rb1;
    __syncthreads();
    if (kt + 32 < K) {
      ra0 = *(const uint4*)(Ap + kt + 32);
      ra1 = *(const uint4*)(Ap + (size_t)64 * K + kt + 32);
      rb0 = *(const uint4*)(Bp + kt + 32);
      rb1 = *(const uint4*)(Bp + (size_t)64 * K + kt + 32);
    }
    short8 af[4], bfr[4];
#pragma unroll
    for (int m = 0; m < 4; ++m)
      af[m] = *(const short8*)&As[(wr * 64 + m * 16 + l15) * LDA + g * 8];
#pragma unroll
    for (int n = 0; n < 4; ++n)
      bfr[n] = *(const short8*)&Bs[(wc * 64 + n * 16 + l15) * LDA + g * 8];
#pragma unroll
    for (int m = 0; m < 4; ++m)
#pragma unroll
      for (int n = 0; n < 4; ++n) acc[m][n] = MFMA16(af[m], bfr[n], acc[m][n]);
  }

#pragma unroll
  for (int m = 0; m < 4; ++m) {
    int row = bm * 128 + wr * 64 + m * 16 + g * 4;
#pragma unroll
    for (int n = 0; n < 4; ++n) {
      int col = bn * 128 + wc * 64 + n * 16 + l15;
      float bv2 = bias[col];
#pragma unroll
      for (int j = 0; j < 4; ++j) {
        float v = (acc[m][n][j] + bv2) * scale;
        int r = row + j;
        int b = r >> 11, s = r & (SEQ - 1), h = col >> 6, hd = col & (HD - 1);
        if (proj < 2)
          outp[((size_t)((b * NH + h) * SEQ + s)) * HD + hd] = f2bf(v);
        else
          outp[((size_t)((b * NH + h) * HD + hd)) * SEQ + s] = f2bf(v);
      }
    }
  }
}

// ---------------- out-proj GEMM (round-5 verified, MODE 1) ----------------
__global__ __launch_bounds__(256) void gemm_out(
    const ushort* __restrict__ A, const ushort* __restrict__ Bt,
    const float* __restrict__ bias, float* __restrict__ outp) {
  constexpr int K = 1024, LDA = 40;
  __shared__ __align__(16) ushort As[128 * LDA];
  __shared__ __align__(16) ushort Bs[128 * LDA];
  const int tid = threadIdx.x;
  const int wave = tid >> 6, lane = tid & 63;
  const int wr = wave >> 1, wc = wave & 1;
  const int g = lane >> 4, l15 = lane & 15;
  const int bm = blockIdx.x, bn = blockIdx.y;
  const int r0 = tid >> 2, c0 = (tid & 3) * 8;
  const ushort* Ap = A + (size_t)(bm * 128 + r0) * K + c0;
  const ushort* Bp = Bt + (size_t)(bn * 128 + r0) * K + c0;
  f32x4 acc[4][4] = {};

  uint4 ra0 = *(const uint4*)(Ap);
  uint4 ra1 = *(const uint4*)(Ap + (size_t)64 * K);
  uint4 rb0 = *(const uint4*)(Bp);
  uint4 rb1 = *(const uint4*)(Bp + (size_t)64 * K);

  for (int kt = 0; kt < K; kt += 32) {
    __syncthreads();
    *(uint4*)&As[r0 * LDA + c0] = ra0;
    *(uint4*)&As[(r0 + 64) * LDA + c0] = ra1;
    *(uint4*)&Bs[r0 * LDA + c0] = rb0;
    *(uint4*)&Bs[(r0 + 64) * LDA + c0] = rb1;
    __syncthreads();
    if (kt + 32 < K) {
      ra0 = *(const uint4*)(Ap + kt + 32);
      ra1 = *(const uint4*)(Ap + (size_t)64 * K + kt + 32);
      rb0 = *(const uint4*)(Bp + kt + 32);
      rb1 = *(const uint4*)(Bp + (size_t)64 * K + kt + 32);
    }
    short8 af[4], bfr[4];
#pragma unroll
    for (int m = 0; m < 4; ++m)
      af[m] = *(const short8*)&As[(wr * 64 + m * 16 + l15) * LDA + g * 8];
#pragma unroll
    for (int n = 0; n < 4; ++n)
      bfr[n] = *(const short8*)&Bs[(wc * 64 + n * 16 + l15) * LDA + g * 8];
#pragma unroll
    for (int m = 0; m < 4; ++m)
#pragma unroll
      for (int n = 0; n < 4; ++n) acc[m][n] = MFMA16(af[m], bfr[n], acc[m][n]);
  }

#pragma unroll
  for (int m = 0; m < 4; ++m) {
    int row = bm * 128 + wr * 64 + m * 16 + g * 4;
#pragma unroll
    for (int n = 0; n < 4; ++n) {
      int col = bn * 128 + wc * 64 + n * 16 + l15;
      float bv = bias[col];
#pragma unroll
      for (int j = 0; j < 4; ++j)
        outp[(size_t)(row + j) * DIM + col] = acc[m][n][j] + bv;
    }
  }
}

// ---------------- flash attention v10: QBLK=64, bh-major block order ----------
// grid 2048 = qt*64 + bh  (bh-major => XCD = bh%8: each head's K/V pinned to one
// XCD's L2; 8 same-qt blocks per XCD share the abias slab). 4 waves; each wave
// owns 16 q-rows. attn5's verified mapping with the sub-dimension deleted.
// LDS 27.6 KB -> 5 blocks/CU; ~75 VGPR.
__global__ __launch_bounds__(256) void attn10(
    const ushort* __restrict__ Q, const ushort* __restrict__ K,
    const ushort* __restrict__ VT, const float* __restrict__ abias,
    const float* __restrict__ kvbias, ushort* __restrict__ X) {
  constexpr int LDK = 72, LDV = 72, LDP = 72;
  __shared__ __align__(16) ushort Ks[64 * LDK];      // [key][d]
  __shared__ __align__(16) ushort Vs[64 * LDV];      // [d][key]  (V^T tile)
  __shared__ __align__(16) ushort Ps[4][16 * LDP];   // per-wave [q_local][key]
  const int tid = threadIdx.x;
  const int w = tid >> 6, lane = tid & 63, g = lane >> 4, l15 = lane & 15;
  const int px = blockIdx.x;
  const int bh = px & 63;          // XCD = bh%8 (natural dispatch order)
  const int qt = px >> 6;          // 0..31
  const int b = bh >> 4, h = bh & (NH - 1);
  const int q0 = qt * 64;

  // Q fragments as A-operand: row = l15, k = c*32 + g*8 (+i)
  short8 qf[2];
  {
    const ushort* qp = Q + ((size_t)bh * SEQ + q0 + w * 16 + l15) * HD;
#pragma unroll
    for (int c = 0; c < 2; ++c) qf[c] = *(const short8*)(qp + c * 32 + g * 8);
  }

  f32x4 o[4] = {};
  float l_lane[4] = {};

  const int sr = tid >> 2, scc = (tid & 3) * 16;
  const ushort* Kp = K + (size_t)bh * SEQ * HD;    // [key][d]
  const ushort* Vp = VT + (size_t)bh * HD * SEQ;   // [d][key]
  const float* abp = abias + (size_t)q0 * SEQ;
  const float* kvp = kvbias + b * SEQ;

  // prologue: tile 0 into regs
  uint4 ka = *(const uint4*)(Kp + (size_t)sr * HD + scc);
  uint4 kb = *(const uint4*)(Kp + (size_t)sr * HD + scc + 8);
  uint4 va = *(const uint4*)(Vp + (size_t)sr * SEQ + scc);
  uint4 vb = *(const uint4*)(Vp + (size_t)sr * SEQ + scc + 8);

  for (int kt = 0; kt < SEQ / 64; ++kt) {
    const int k0 = kt * 64;
    __syncthreads();  // previous tile's LDS reads complete
    *(uint4*)&Ks[sr * LDK + scc] = ka;
    *(uint4*)&Ks[sr * LDK + scc + 8] = kb;
    *(uint4*)&Vs[sr * LDV + scc] = va;
    *(uint4*)&Vs[sr * LDV + scc + 8] = vb;
    __syncthreads();

    // this tile's bias loads (fp32, exact), issued ahead of consumption
    float bkv[4];
#pragma unroll
    for (int ct = 0; ct < 4; ++ct) bkv[ct] = kvp[k0 + ct * 16 + l15];
    float abf[4][4];
#pragma unroll
    for (int j = 0; j < 4; ++j) {
      const float* abr = abp + (size_t)(w * 16 + 4 * g + j) * SEQ + k0 + l15;
#pragma unroll
      for (int ct = 0; ct < 4; ++ct) abf[ct][j] = abr[ct * 16];
    }

    // prefetch next tile into regs (overlaps all of this tile's compute)
    if (kt + 1 < SEQ / 64) {
      ka = *(const uint4*)(Kp + (size_t)(k0 + 64 + sr) * HD + scc);
      kb = *(const uint4*)(Kp + (size_t)(k0 + 64 + sr) * HD + scc + 8);
      va = *(const uint4*)(Vp + (size_t)sr * SEQ + k0 + 64 + scc);
      vb = *(const uint4*)(Vp + (size_t)sr * SEQ + k0 + 64 + scc + 8);
    }

    // S = Q K^T : rows q (D: 4g+j), cols key (D: l15). 4 key-chunks.
    f32x4 s4[4];
#pragma unroll
    for (int ct = 0; ct < 4; ++ct) {
      short8 kf0 = *(const short8*)&Ks[(ct * 16 + l15) * LDK + g * 8];
      short8 kf1 = *(const short8*)&Ks[(ct * 16 + l15) * LDK + 32 + g * 8];
      f32x4 z = {0.f, 0.f, 0.f, 0.f};
      f32x4 t = MFMA16(qf[0], kf0, z);
      s4[ct] = MFMA16(qf[1], kf1, t);
    }

    // no-max softmax in exp2 domain; per-lane l partials (no in-loop reductions)
    {
      float p[4][4];
#pragma unroll
      for (int ct = 0; ct < 4; ++ct)
#pragma unroll
        for (int j = 0; j < 4; ++j)
          p[ct][j] = exp2fn(fmaf(abf[ct][j] + bkv[ct], LOG2E, s4[ct][j]));
#pragma unroll
      for (int j = 0; j < 4; ++j)
        l_lane[j] += (p[0][j] + p[1][j]) + (p[2][j] + p[3][j]);
#pragma unroll
      for (int ct = 0; ct < 4; ++ct)
#pragma unroll
        for (int j = 0; j < 4; ++j)
          Ps[w][(4 * g + j) * LDP + ct * 16 + l15] = bf1(p[ct][j]);
    }

    // wave-private P ready
    asm volatile("s_waitcnt lgkmcnt(0)" ::: "memory");
    __builtin_amdgcn_sched_barrier(0);

    // O += P V  (P as A: row=l15; V^T as B: col=l15=d)
    short8 pa[2];
#pragma unroll
    for (int ks = 0; ks < 2; ++ks)
      pa[ks] = *(const short8*)&Ps[w][l15 * LDP + ks * 32 + g * 8];
#pragma unroll
    for (int ctd = 0; ctd < 4; ++ctd) {
      short8 vf0 = *(const short8*)&Vs[(ctd * 16 + l15) * LDV + g * 8];
      short8 vf1 = *(const short8*)&Vs[(ctd * 16 + l15) * LDV + 32 + g * 8];
      o[ctd] = MFMA16(pa[0], vf0, o[ctd]);
      o[ctd] = MFMA16(pa[1], vf1, o[ctd]);
    }
  }

  // one final l reduction per row (16-lane l15 group), then normalize + write
  float inv[4];
#pragma unroll
  for (int j = 0; j < 4; ++j) {
    float l = l_lane[j];
    l += __shfl_xor(l, 1);
    l += __shfl_xor(l, 2);
    l += __shfl_xor(l, 4);
    l += __shfl_xor(l, 8);
    inv[j] = 1.0f / l;
  }
#pragma unroll
  for (int ctd = 0; ctd < 4; ++ctd)
#pragma unroll
    for (int j = 0; j < 4; ++j) {
      size_t row = (size_t)b * SEQ + q0 + w * 16 + 4 * g + j;
      X[row * DIM + h * HD + ctd * 16 + l15] = bf1(o[ctd][j] * inv[j]);
    }
}

extern "C" void kernel_launch(void* const* d_in, const int* in_sizes, int n_in,
                              void* d_out, int out_size, void* d_ws, size_t ws_size,
                              hipStream_t stream) {
  const float* inputs_q = (const float*)d_in[0];
  const float* pos_q = (const float*)d_in[1];
  const float* pos_k = (const float*)d_in[2];
  const float* pos_v = (const float*)d_in[3];
  const float* abias = (const float*)d_in[4];
  const float* kvbias = (const float*)d_in[5];
  const float* wq = (const float*)d_in[6];
  const float* bq = (const float*)d_in[7];
  const float* wk = (const float*)d_in[8];
  const float* bk = (const float*)d_in[9];
  const float* wv = (const float*)d_in[10];
  const float* bv = (const float*)d_in[11];
  const float* wo = (const float*)d_in[12];
  const float* bo = (const float*)d_in[13];

  char* ws = (char*)d_ws;
  const size_t MB = 1ull << 20;
  ushort* wqT = (ushort*)(ws + 0 * MB);
  ushort* wkT = (ushort*)(ws + 2 * MB);
  ushort* wvT = (ushort*)(ws + 4 * MB);
  ushort* woT = (ushort*)(ws + 6 * MB);
  ushort* aq = (ushort*)(ws + 8 * MB);
  ushort* ak = (ushort*)(ws + 24 * MB);
  ushort* av = (ushort*)(ws + 40 * MB);
  ushort* Qb = (ushort*)(ws + 56 * MB);
  ushort* Kb = (ushort*)(ws + 72 * MB);
  ushort* VTb = (ushort*)(ws + 88 * MB);
  ushort* Xb = (ushort*)(ws + 8 * MB);  // alias aq (dead after Q-GEMM)

  prep_a<<<8192, 256, 0, stream>>>(inputs_q, pos_q, pos_k, pos_v, aq, ak, av);
  transpose_all<<<dim3(32, 32, 4), 256, 0, stream>>>(wq, wk, wv, wo, wqT, wkT, wvT, woT);
  gemm_qkv<<<dim3(64, 24), 256, 0, stream>>>(aq, ak, av, wqT, wkT, wvT,
                                             bq, bk, bv, Qb, Kb, VTb);
  attn10<<<2048, 256, 0, stream>>>(Qb, Kb, VTb, abias, kvbias, Xb);
  gemm_out<<<dim3(64, 8), 256, 0, stream>>>(Xb, woT, bo, (float*)d_out);
}